// Round 4
// baseline (257.883 us; speedup 1.0000x reference)
//
#include <hip/hip_runtime.h>
#include <hip/hip_bf16.h>
#include <cstddef>

#define BB 16
#define TT 4096
#define HH 512

typedef _Float16 half8 __attribute__((ext_vector_type(8)));
typedef float f32x4 __attribute__((ext_vector_type(4)));

__device__ __forceinline__ float fast_rcp(float x) { return __builtin_amdgcn_rcpf(x); }

#define ASM_VMCNT8() { asm volatile("s_waitcnt vmcnt(8)" ::: "memory"); __builtin_amdgcn_sched_barrier(0); }
#define ASM_VMCNT0() { asm volatile("s_waitcnt vmcnt(0)" ::: "memory"); __builtin_amdgcn_sched_barrier(0); }
#define ASM_LGKM0()  { asm volatile("s_waitcnt lgkmcnt(0)" ::: "memory"); __builtin_amdgcn_sched_barrier(0); }

// ---------------- prep (unchanged) ---------------------------------------------
// blocks 0..127 : pack Wv (f32 [n][k]) -> Bpack f16, layout [kb(16)][tn(32)][lane(64)][8]
// blocks 128..191: qb[b][o] = query[b]·Wq[o] + bias[o] + conv_b[o]
// block  192     : zero ssum/ctx
__global__ void prep_kernel(const float* __restrict__ query,
                            const float* __restrict__ conv_b,
                            const float* __restrict__ Wq,
                            const float* __restrict__ Wv,
                            const float* __restrict__ bias,
                            _Float16* __restrict__ Bpack,
                            float* __restrict__ qb,
                            float* __restrict__ ssum,
                            float* __restrict__ ctx) {
    int blk = blockIdx.x;
    int tid = threadIdx.x;
    if (blk < 128) {
        int tn = blk >> 2, kq = blk & 3;
        int kb = kq * 4 + (tid >> 6);
        int lane = tid & 63;
        int n = tn * 16 + (lane & 15);
        int k = kb * 32 + ((lane >> 4) << 3);
        const float4* src = (const float4*)(Wv + (size_t)n * HH + k);
        float4 v0 = src[0], v1 = src[1];
        half8 h = { (_Float16)v0.x, (_Float16)v0.y, (_Float16)v0.z, (_Float16)v0.w,
                    (_Float16)v1.x, (_Float16)v1.y, (_Float16)v1.z, (_Float16)v1.w };
        *(half8*)(Bpack + ((size_t)(kb * 32 + tn) * 64 + lane) * 8) = h;
    } else if (blk < 192) {
        int q = blk - 128;
        int b = q >> 2, oq = q & 3;
        __shared__ float qrow[HH];
        for (int i = tid; i < HH; i += 256) qrow[i] = query[b * HH + i];
        __syncthreads();
        int wave = tid >> 6, lane = tid & 63;
        float4 q1 = *(const float4*)(qrow + lane * 8);
        float4 q2 = *(const float4*)(qrow + lane * 8 + 4);
        for (int i = wave; i < 128; i += 4) {
            int o = oq * 128 + i;
            const float4* w = (const float4*)(Wq + (size_t)o * HH);
            float4 a = w[lane * 2], c = w[lane * 2 + 1];
            float acc = a.x * q1.x + a.y * q1.y + a.z * q1.z + a.w * q1.w
                      + c.x * q2.x + c.y * q2.y + c.z * q2.z + c.w * q2.w;
            #pragma unroll
            for (int off = 1; off < 64; off <<= 1) acc += __shfl_xor(acc, off, 64);
            if (lane == 0) qb[b * HH + o] = acc + bias[o] + conv_b[o];
        }
    } else {
        for (int i = tid; i < BB; i += 256) ssum[i] = 0.f;
        for (int i = tid; i < BB * HH; i += 256) ctx[i] = 0.f;
    }
}

// ---------------- fused GEMM + conv + tanh + score + sigmoid + context ---------
// Persistent-block stream design (T3+T4 minimum-2-phase):
//   grid 256 = 1 block/CU; block 512 thr = 8 waves; each block owns b = blk>>4
//   and 8 t-tiles of 32 rows: t0 = ((blk&15) + 16*j)*32, j=0..7.
//   B-fragments (16 kb x 2 nt half8 = 128 VGPR) persistent across tiles.
//   A staged f32 via global_load_lds width-16, double-buffered LDS
//   [2][32 rows][516 f32] (row stride +16B pad -> fragment ds_reads 2-way/bank
//   = free, DMA dest linear, no swizzle).  f32->f16 cvt at fragment read (RNE,
//   same rounding as before).  Raw s_barrier + counted vmcnt(8): tile j+1's 8
//   DMA-loads/wave stay in flight across tile j's compute (never vmcnt(0) in
//   the loop).  ctx/ssum accumulated in registers across tiles -> 1 atomic each
//   at the end.  Score structure (o = ng*32+nt*16+lm) preserved exactly.
__global__ __launch_bounds__(512, 2) void gemm_fused_kernel(
        const float* __restrict__ value,
        const float* __restrict__ last_attn,
        const float* __restrict__ conv_w,
        const float* __restrict__ w_score,
        const float* __restrict__ b_score,
        const _Float16* __restrict__ Bpack,
        const float* __restrict__ qb,
        float* __restrict__ sbuf,
        float* __restrict__ ssum,
        float* __restrict__ ctx) {
    extern __shared__ float Asf[];      // 2 * 32 * 516 f32 = 132096 B
    __shared__ float sred[32][9];
    __shared__ float s_lds[32];

    int tid = threadIdx.x;
    int blk = blockIdx.x;
    int b = blk >> 4;
    int ts = blk & 15;                  // tile stride base: tj = ts + 16*j

    int lane = tid & 63, ng = tid >> 6;
    int quad = lane >> 4, lm = lane & 15;

    // ---- persistent B fragments: 16 kb x 2 nt, tn = 2*ng + nt (as before) ----
    const _Float16* bp0 = Bpack + (size_t)(ng * 2) * 512 + lane * 8;
    half8 breg[16][2];
    #pragma unroll
    for (int kb = 0; kb < 16; ++kb)
        #pragma unroll
        for (int nt = 0; nt < 2; ++nt)
            breg[kb][nt] = *(const half8*)(bp0 + (size_t)kb * 16384 + nt * 512);

    // ---- epilogue scalars (o = ng*32 + nt*16 + lm, preserved) ----
    float qvv[2], c0v[2], c1v[2], c2v[2], wvv[2];
    #pragma unroll
    for (int nt = 0; nt < 2; ++nt) {
        int o = ng * 32 + nt * 16 + lm;
        qvv[nt] = qb[b * HH + o];
        c0v[nt] = conv_w[o * 3 + 0];
        c1v[nt] = conv_w[o * 3 + 1];
        c2v[nt] = conv_w[o * 3 + 2];
        wvv[nt] = w_score[o];
    }
    float bsc = b_score[0];

    // ---- DMA stage: wave ng stages rows ng*4..ng*4+3, 2 instrs/row ----
    auto STAGE = [&](int buf, int tj) {
        const float* gbase = value + ((size_t)b * TT + (size_t)tj * 32) * HH;
        float* lbase = Asf + buf * 16512;
        #pragma unroll
        for (int rr = 0; rr < 4; ++rr) {
            int row = ng * 4 + rr;
            #pragma unroll
            for (int hf = 0; hf < 2; ++hf) {
                const float* g = gbase + (size_t)row * HH + hf * 256 + lane * 4;
                float* l = lbase + row * 516 + hf * 256;
                __builtin_amdgcn_global_load_lds(
                    (const __attribute__((address_space(1))) void*)g,
                    (__attribute__((address_space(3))) void*)l, 16, 0, 0);
            }
        }
    };

    // prologue: tiles 0 and 1 in flight
    STAGE(0, ts);
    STAGE(1, ts + 16);

    float ctx_acc = 0.f;
    float tot_acc = 0.f;

    for (int j = 0; j < 8; ++j) {
        int tj = ts + 16 * j;
        int t0 = tj * 32;
        float* As = Asf + (j & 1) * 16512;

        // B1: tile j landed (tile j+1's 8 loads stay outstanding)
        if (j < 7) { ASM_VMCNT8(); } else { ASM_VMCNT0(); }
        __builtin_amdgcn_s_barrier();

        // last_attn neighborhood (regs; latency hides under K-loop)
        float la[2][6];
        #pragma unroll
        for (int mt = 0; mt < 2; ++mt) {
            int tg0 = t0 + mt * 16 + quad * 4;
            #pragma unroll
            for (int u = 0; u < 6; ++u) {
                int tg = tg0 - 1 + u;
                la[mt][u] = (tg >= 0 && tg < TT) ? last_attn[(size_t)b * TT + tg] : 0.f;
            }
        }

        // ---- K-loop: f32 frags from LDS -> f16 -> MFMA ----
        f32x4 acc[2][2];
        #pragma unroll
        for (int mt = 0; mt < 2; ++mt)
            #pragma unroll
            for (int nt = 0; nt < 2; ++nt) { f32x4 z = {0.f,0.f,0.f,0.f}; acc[mt][nt] = z; }

        #pragma unroll
        for (int kb = 0; kb < 16; ++kb) {
            #pragma unroll
            for (int mt = 0; mt < 2; ++mt) {
                const float* p = As + (mt * 16 + lm) * 516 + kb * 32 + quad * 8;
                f32x4 a0 = *(const f32x4*)p;
                f32x4 a1 = *(const f32x4*)(p + 4);
                half8 a = { (_Float16)a0.x, (_Float16)a0.y, (_Float16)a0.z, (_Float16)a0.w,
                            (_Float16)a1.x, (_Float16)a1.y, (_Float16)a1.z, (_Float16)a1.w };
                #pragma unroll
                for (int nt = 0; nt < 2; ++nt)
                    acc[mt][nt] = __builtin_amdgcn_mfma_f32_16x16x32_f16(a, breg[kb][nt], acc[mt][nt], 0, 0, 0);
            }
        }

        // ---- epilogue: conv + tanh + w_score dot ----
        #pragma unroll
        for (int mt = 0; mt < 2; ++mt) {
            float rsj[4];
            #pragma unroll
            for (int jj = 0; jj < 4; ++jj) {
                float lam = la[mt][jj];
                float la0 = la[mt][jj + 1];
                float lap = la[mt][jj + 2];
                float r = 0.f;
                #pragma unroll
                for (int nt = 0; nt < 2; ++nt) {
                    float act = acc[mt][nt][jj] + qvv[nt]
                              + c0v[nt] * lam + c1v[nt] * la0 + c2v[nt] * lap;
                    act = fminf(15.f, fmaxf(-15.f, act));
                    float e2 = __expf(2.f * act);
                    r += (1.f - 2.f * fast_rcp(e2 + 1.f)) * wvv[nt];
                }
                #pragma unroll
                for (int off = 1; off < 16; off <<= 1) r += __shfl_xor(r, off, 64);
                rsj[jj] = r;
            }
            if (lm == 0)
                #pragma unroll
                for (int jj = 0; jj < 4; ++jj)
                    sred[mt * 16 + quad * 4 + jj][ng] = rsj[jj];
        }
        ASM_LGKM0();
        __builtin_amdgcn_s_barrier();   // B2: sred visible

        if (tid < 32) {
            float sc = bsc;
            #pragma unroll
            for (int k = 0; k < 8; ++k) sc += sred[tid][k];
            float s = fast_rcp(1.f + __expf(-sc));
            s_lds[tid] = s;
            sbuf[(size_t)b * TT + t0 + tid] = s;
            tot_acc += s;
        }
        ASM_LGKM0();
        __builtin_amdgcn_s_barrier();   // B3: s_lds visible

        // ---- context partial from resident f32 tile: one column per thread ----
        {
            float a = 0.f;
            #pragma unroll 8
            for (int t2 = 0; t2 < 32; ++t2)
                a += s_lds[t2] * As[t2 * 516 + tid];
            ctx_acc += a;
        }
        ASM_LGKM0();
        __builtin_amdgcn_s_barrier();   // B4: all waves done reading buf

        if (j < 6) STAGE(j & 1, ts + 16 * (j + 2));
    }

    atomicAdd(&ctx[b * HH + tid], ctx_acc);
    if (tid < 64) {
        float tot = tot_acc;            // lanes 32..63 contribute 0
        #pragma unroll
        for (int off = 1; off < 64; off <<= 1) tot += __shfl_xor(tot, off, 64);
        if (tid == 0) atomicAdd(&ssum[b], tot);
    }
}

// ---------------- finalize: out = [ctx/ssum, query] ++ attn = s/ssum -----------
__global__ void finalize_kernel(const float* __restrict__ query,
                                const float* __restrict__ ctx,
                                const float* __restrict__ sbuf,
                                const float* __restrict__ ssum,
                                float* __restrict__ out) {
    int idx = blockIdx.x * 256 + threadIdx.x;
    if (idx < BB * 2 * HH) {
        int b = idx >> 10, c = idx & 1023;
        float v;
        if (c < HH) v = ctx[b * HH + c] / ssum[b];
        else        v = query[b * HH + (c - HH)];
        out[idx] = v;
    } else {
        int j = idx - BB * 2 * HH;
        int b = j >> 12, t = j & 4095;
        out[idx] = sbuf[b * TT + t] / ssum[b];
    }
}

extern "C" void kernel_launch(void* const* d_in, const int* in_sizes, int n_in,
                              void* d_out, int out_size, void* d_ws, size_t ws_size,
                              hipStream_t stream) {
    const float* query     = (const float*)d_in[0];
    const float* value     = (const float*)d_in[1];
    const float* last_attn = (const float*)d_in[2];
    const float* conv_w    = (const float*)d_in[3];
    const float* conv_b    = (const float*)d_in[4];
    const float* Wq        = (const float*)d_in[5];
    const float* Wv        = (const float*)d_in[6];
    const float* bias      = (const float*)d_in[7];
    const float* w_score   = (const float*)d_in[8];
    const float* b_score   = (const float*)d_in[9];

    char* ws = (char*)d_ws;
    _Float16* Bpack = (_Float16*)ws;           // 524288 B
    float* qb     = (float*)(ws + 524288);     // 32768 B
    float* sbuf   = (float*)(ws + 557056);     // 262144 B
    float* ssum   = (float*)(ws + 819200);     // 64 B
    float* ctx    = (float*)(ws + 819264);     // 32768 B
    float* out    = (float*)d_out;

    static bool attr_set = false;
    if (!attr_set) {
        hipFuncSetAttribute((const void*)gemm_fused_kernel,
                            hipFuncAttributeMaxDynamicSharedMemorySize, 132096);
        attr_set = true;
    }

    prep_kernel<<<193, 256, 0, stream>>>(query, conv_b, Wq, Wv, bias, Bpack, qb, ssum, ctx);
    gemm_fused_kernel<<<256, 512, 132096, stream>>>(value, last_attn, conv_w, w_score,
                                                    b_score, Bpack, qb, sbuf, ssum, ctx);
    finalize_kernel<<<320, 256, 0, stream>>>(query, ctx, sbuf, ssum, out);
}